// Round 2
// baseline (5962.840 us; speedup 1.0000x reference)
//
#include <hip/hip_runtime.h>
#include <hip/hip_bf16.h>
#include <math.h>

#define CC 120       // channels
#define NHEADS 6
#define HDIM 20      // head dim
#define NTOK 128     // tokens per window
#define HID2 240
#define SCALE_F 0.2236067977499790f  // 20^-0.5

typedef __hip_bfloat16 bf16;

// ---------------------------------------------------------------------------
// token -> (window, intra) -> rolled spatial source position (also the store
// destination for window-reverse + un-roll, which is the same map).
// wi = ((b*4 + dB)*8 + hB)*8 + wB ; n = dI*64 + hI*8 + wI
__device__ inline size_t token_src_offset(int token) {
  const int wi = token >> 7, n = token & 127;
  const int b_ = wi >> 8, rem = wi & 255;
  const int dB = rem >> 6, hB = (rem >> 3) & 7, wB = rem & 7;
  const int dI = n >> 6, hI = (n >> 3) & 7, wI = n & 7;
  const int d = dB * 2 + dI, h = hB * 8 + hI, w = wB * 8 + wI;
  const int ds = (d + 1) & 7, hs = (h + 4) & 63, ws2 = (w + 4) & 63;
  return (((size_t)(b_ * 8 + ds) * 64 + hs) * 64 + ws2) * CC;
}

// In-register LayerNorm over 120 channels.
__device__ inline void ln120(float* xv, const float* __restrict__ g,
                             const float* __restrict__ bb) {
  float s0 = 0.f, s1 = 0.f, s2 = 0.f, s3 = 0.f;
#pragma unroll
  for (int k = 0; k < CC; k += 4) {
    s0 += xv[k]; s1 += xv[k + 1]; s2 += xv[k + 2]; s3 += xv[k + 3];
  }
  const float mean = ((s0 + s1) + (s2 + s3)) * (1.f / 120.f);
  float v0 = 0.f, v1 = 0.f, v2 = 0.f, v3 = 0.f;
#pragma unroll
  for (int k = 0; k < CC; k += 4) {
    float d0 = xv[k] - mean, d1 = xv[k + 1] - mean;
    float d2 = xv[k + 2] - mean, d3 = xv[k + 3] - mean;
    v0 += d0 * d0; v1 += d1 * d1; v2 += d2 * d2; v3 += d3 * d3;
  }
  const float rstd = rsqrtf(((v0 + v1) + (v2 + v3)) * (1.f / 120.f) + 1e-5f);
#pragma unroll
  for (int k = 0; k < CC; k++) xv[k] = (xv[k] - mean) * rstd * g[k] + bb[k];
}

__device__ inline float dot120(const float* xv, const float* __restrict__ wr) {
  float a0 = 0.f, a1 = 0.f, a2 = 0.f, a3 = 0.f;
#pragma unroll
  for (int k = 0; k < CC; k += 4) {
    a0 = fmaf(xv[k], wr[k], a0);
    a1 = fmaf(xv[k + 1], wr[k + 1], a1);
    a2 = fmaf(xv[k + 2], wr[k + 2], a2);
    a3 = fmaf(xv[k + 3], wr[k + 3], a3);
  }
  return (a0 + a1) + (a2 + a3);
}

// ---------------------------------------------------------------------------
// Self attention, fully fused: LN + roll + partition + QKV(head slice) + attn.
// Block = (window, head), thread = token. One-pass softmax (no max: scores
// bounded by ~+1.5, masked entries are -100 -> exp underflows to 0 safely).
__global__ __launch_bounds__(128) void k_attn_self(
    const float* __restrict__ x, const float* __restrict__ g1,
    const float* __restrict__ b1, const float* __restrict__ wqkv,
    const float* __restrict__ bqkv, const float* __restrict__ mask,
    const float* __restrict__ rpb, const int* __restrict__ rpi,
    bf16* __restrict__ xout) {
  __shared__ float kl[NTOK][HDIM];
  __shared__ float vl[NTOK][HDIM];
  const int wi = blockIdx.x, hh = blockIdx.y, t = threadIdx.x;
  const int token = wi * NTOK + t;
  const float* xr = x + token_src_offset(token);
  float xv[CC];
#pragma unroll
  for (int k = 0; k < CC; k++) xv[k] = xr[k];
  ln120(xv, g1, b1);
  float q[HDIM];
  for (int j = 0; j < HDIM; j++) {
    const int c = hh * HDIM + j;
    q[j] = (dot120(xv, wqkv + (size_t)c * CC) + bqkv[c]) * SCALE_F;
    kl[t][j] = dot120(xv, wqkv + (size_t)(CC + c) * CC) + bqkv[CC + c];
    vl[t][j] = dot120(xv, wqkv + (size_t)(2 * CC + c) * CC) + bqkv[2 * CC + c];
  }
  __syncthreads();
  const float* mrow = mask + ((size_t)(wi & 255) * NTOK + t) * NTOK;
  const int* rrow = rpi + t * NTOK;
  float sum = 0.f;
  float o[HDIM];
#pragma unroll
  for (int i = 0; i < HDIM; i++) o[i] = 0.f;
  for (int m = 0; m < NTOK; m++) {
    float a0 = 0.f, a1 = 0.f, a2 = 0.f, a3 = 0.f;
#pragma unroll
    for (int i = 0; i < HDIM; i += 4) {
      a0 = fmaf(q[i], kl[m][i], a0);
      a1 = fmaf(q[i + 1], kl[m][i + 1], a1);
      a2 = fmaf(q[i + 2], kl[m][i + 2], a2);
      a3 = fmaf(q[i + 3], kl[m][i + 3], a3);
    }
    const float sc = (a0 + a1) + (a2 + a3) + rpb[rrow[m] * NHEADS + hh] + mrow[m];
    const float p = __expf(sc);
    sum += p;
#pragma unroll
    for (int i = 0; i < HDIM; i++) o[i] = fmaf(p, vl[m][i], o[i]);
  }
  const float inv = 1.f / sum;
  bf16* orow = xout + ((size_t)token) * HID2 + CC + hh * HDIM;
#pragma unroll
  for (int i = 0; i < HDIM; i++) orow[i] = __float2bfloat16(o[i] * inv);
}

// ---------------------------------------------------------------------------
// Mutual attention, fully fused. Block = (window, head, which).
// which=0: x1 = attn(q2, k1, v1) -> out rows 0..63
// which=1: x2 = attn(q1, k2, v2) -> out rows 64..127
// Thread t processes kv-token first (k,v -> LDS), then q-token, reusing regs.
__global__ __launch_bounds__(64) void k_attn_mut(
    const float* __restrict__ x, const float* __restrict__ g1,
    const float* __restrict__ b1, const float* __restrict__ wqkv,
    const float* __restrict__ bqkv, const float* __restrict__ pos,
    const float* __restrict__ mask, bf16* __restrict__ xout) {
  __shared__ float kl[64][HDIM];
  __shared__ float vl[64][HDIM];
  const int wi = blockIdx.x, hh = blockIdx.y, which = blockIdx.z;
  const int t = threadIdx.x;
  const int qtok = which ? t : 64 + t;
  const int ktok = which ? 64 + t : t;
  const float* pr = pos + (size_t)t * CC;  // (qtok&63) == (ktok&63) == t
  float xv[CC];
  // kv row
  {
    const float* xr = x + token_src_offset(wi * NTOK + ktok);
#pragma unroll
    for (int k = 0; k < CC; k++) xv[k] = xr[k];
    ln120(xv, g1, b1);
#pragma unroll
    for (int k = 0; k < CC; k++) xv[k] += pr[k];
    for (int j = 0; j < HDIM; j++) {
      const int c = hh * HDIM + j;
      kl[t][j] = dot120(xv, wqkv + (size_t)(CC + c) * CC) + bqkv[CC + c];
      vl[t][j] = dot120(xv, wqkv + (size_t)(2 * CC + c) * CC) + bqkv[2 * CC + c];
    }
  }
  // q row
  float q[HDIM];
  {
    const float* xr = x + token_src_offset(wi * NTOK + qtok);
#pragma unroll
    for (int k = 0; k < CC; k++) xv[k] = xr[k];
    ln120(xv, g1, b1);
#pragma unroll
    for (int k = 0; k < CC; k++) xv[k] += pr[k];
    for (int j = 0; j < HDIM; j++) {
      const int c = hh * HDIM + j;
      q[j] = (dot120(xv, wqkv + (size_t)c * CC) + bqkv[c]) * SCALE_F;
    }
  }
  __syncthreads();
  const float* mrow = mask + ((size_t)(wi & 255) * NTOK + t) * NTOK;  // mask[:64,:64]
  float sum = 0.f;
  float o[HDIM];
#pragma unroll
  for (int i = 0; i < HDIM; i++) o[i] = 0.f;
  for (int m = 0; m < 64; m++) {
    float a0 = 0.f, a1 = 0.f, a2 = 0.f, a3 = 0.f;
#pragma unroll
    for (int i = 0; i < HDIM; i += 4) {
      a0 = fmaf(q[i], kl[m][i], a0);
      a1 = fmaf(q[i + 1], kl[m][i + 1], a1);
      a2 = fmaf(q[i + 2], kl[m][i + 2], a2);
      a3 = fmaf(q[i + 3], kl[m][i + 3], a3);
    }
    const float p = __expf((a0 + a1) + (a2 + a3) + mrow[m]);
    sum += p;
#pragma unroll
    for (int i = 0; i < HDIM; i++) o[i] = fmaf(p, vl[m][i], o[i]);
  }
  const float inv = 1.f / sum;
  const int orow_i = which ? 64 + t : t;
  bf16* orow = xout + ((size_t)(wi * NTOK + orow_i)) * HID2 + hh * HDIM;
#pragma unroll
  for (int i = 0; i < HDIM; i++) orow[i] = __float2bfloat16(o[i] * inv);
}

// ---------------------------------------------------------------------------
// proj (K=240 split in two K=120 passes) + window reverse + un-roll + residual.
template <int HALF>
__global__ __launch_bounds__(256) void k_proj(
    const bf16* __restrict__ xout, const float* __restrict__ pw,
    const float* __restrict__ pb, const float* __restrict__ xin,
    float* __restrict__ out) {
  const int token = blockIdx.x * 256 + threadIdx.x;
  float xv[CC];
  const bf16* xr = xout + (size_t)token * HID2 + HALF * CC;
#pragma unroll
  for (int k = 0; k < CC; k++) xv[k] = __bfloat162float(xr[k]);
  const size_t dst = token_src_offset(token);
  for (int o = 0; o < CC; o++) {
    const float acc = dot120(xv, pw + (size_t)o * HID2 + HALF * CC);
    if (HALF == 0)
      out[dst + o] = xin[dst + o] + pb[o] + acc;
    else
      out[dst + o] += acc;
  }
}

// ---------------------------------------------------------------------------
// FFN part 1: LN2 + fc11 + fc12 + exact GELU * gate -> hidden (bf16, 131072x240)
__global__ __launch_bounds__(256) void k_ffn1(
    const float* __restrict__ xres, const float* __restrict__ g,
    const float* __restrict__ bb, const float* __restrict__ w11,
    const float* __restrict__ b11, const float* __restrict__ w12,
    const float* __restrict__ b12, bf16* __restrict__ hbuf) {
  const int row = blockIdx.x * 256 + threadIdx.x;
  const float* xr = xres + (size_t)row * CC;
  float xv[CC];
#pragma unroll
  for (int k = 0; k < CC; k++) xv[k] = xr[k];
  ln120(xv, g, bb);
  bf16* hr = hbuf + (size_t)row * HID2;
  for (int o = 0; o < HID2; o++) {
    const float a = b11[o] + dot120(xv, w11 + (size_t)o * CC);
    const float c = b12[o] + dot120(xv, w12 + (size_t)o * CC);
    const float ge = 0.5f * a * (1.f + erff(a * 0.70710678118654752f));
    hr[o] = __float2bfloat16(ge * c);
  }
}

// ---------------------------------------------------------------------------
// FFN part 2: out += hidden @ fc2_w.T + fc2_b  (two K=120 passes)
template <int HALF>
__global__ __launch_bounds__(256) void k_ffn2(
    const bf16* __restrict__ hbuf, const float* __restrict__ w2,
    const float* __restrict__ b2f, float* __restrict__ out) {
  const int row = blockIdx.x * 256 + threadIdx.x;
  float xv[CC];
  const bf16* xr = hbuf + (size_t)row * HID2 + HALF * CC;
#pragma unroll
  for (int k = 0; k < CC; k++) xv[k] = __bfloat162float(xr[k]);
  float* orow = out + (size_t)row * CC;
  for (int o = 0; o < CC; o++) {
    float acc = dot120(xv, w2 + (size_t)o * HID2 + HALF * CC);
    if (HALF == 0) acc += b2f[o];
    orow[o] += acc;
  }
}

// ---------------------------------------------------------------------------
extern "C" void kernel_launch(void* const* d_in, const int* in_sizes, int n_in,
                              void* d_out, int out_size, void* d_ws, size_t ws_size,
                              hipStream_t stream) {
  const float* x          = (const float*)d_in[0];
  const float* attn_mask  = (const float*)d_in[1];
  const float* g1         = (const float*)d_in[2];
  const float* b1         = (const float*)d_in[3];
  const float* qkv_self_w = (const float*)d_in[4];
  const float* qkv_self_b = (const float*)d_in[5];
  const float* qkv_mut_w  = (const float*)d_in[6];
  const float* qkv_mut_b  = (const float*)d_in[7];
  const float* proj_w     = (const float*)d_in[8];
  const float* proj_b     = (const float*)d_in[9];
  const float* rpb_table  = (const float*)d_in[10];
  const float* pos_bias   = (const float*)d_in[11];
  const float* g2         = (const float*)d_in[12];
  const float* b2         = (const float*)d_in[13];
  const float* fc11_w     = (const float*)d_in[14];
  const float* fc11_b     = (const float*)d_in[15];
  const float* fc12_w     = (const float*)d_in[16];
  const float* fc12_b     = (const float*)d_in[17];
  const float* fc2_w      = (const float*)d_in[18];
  const float* fc2_b      = (const float*)d_in[19];
  const int*   rpi        = (const int*)d_in[20];
  float* out = (float*)d_out;

  // Workspace: ONE bf16 buffer of 131072 x 240 (62.9 MB). Holds the attention
  // concat output (xout) for proj, then is reused as the FFN hidden buffer.
  bf16* xout = (bf16*)d_ws;
  bf16* hbuf = (bf16*)d_ws;

  k_attn_self<<<dim3(1024, NHEADS), 128, 0, stream>>>(
      x, g1, b1, qkv_self_w, qkv_self_b, attn_mask, rpb_table, rpi, xout);
  k_attn_mut<<<dim3(1024, NHEADS, 2), 64, 0, stream>>>(
      x, g1, b1, qkv_mut_w, qkv_mut_b, pos_bias, attn_mask, xout);
  k_proj<0><<<512, 256, 0, stream>>>(xout, proj_w, proj_b, x, out);
  k_proj<1><<<512, 256, 0, stream>>>(xout, proj_w, proj_b, x, out);
  k_ffn1<<<512, 256, 0, stream>>>(out, g2, b2, fc11_w, fc11_b, fc12_w, fc12_b, hbuf);
  k_ffn2<0><<<512, 256, 0, stream>>>(hbuf, fc2_w, fc2_b, out);
  k_ffn2<1><<<512, 256, 0, stream>>>(hbuf, fc2_w, fc2_b, out);
}

// Round 3
// 2466.223 us; speedup vs baseline: 2.4178x; 2.4178x over previous
//
#include <hip/hip_runtime.h>
#include <hip/hip_bf16.h>
#include <math.h>

#define CC 120       // channels
#define NHEADS 6
#define HDIM 20      // head dim
#define NTOK 128     // tokens per window
#define HID2 240
#define SCALE_F 0.2236067977499790f  // 20^-0.5

typedef __hip_bfloat16 bf16;
typedef __attribute__((ext_vector_type(8))) short bf16x8;   // 8 bf16 (4 VGPRs)
typedef __attribute__((ext_vector_type(4))) float f32x4;    // MFMA accumulator

__device__ inline f32x4 mfma16(bf16x8 a, bf16x8 b, f32x4 c) {
  return __builtin_amdgcn_mfma_f32_16x16x32_bf16(a, b, c, 0, 0, 0);
}

// ---------------------------------------------------------------------------
// token -> rolled spatial source position (also the scatter destination for
// window-reverse + un-roll, which is the same map).
__device__ inline size_t token_src_offset(int token) {
  const int wi = token >> 7, n = token & 127;
  const int b_ = wi >> 8, rem = wi & 255;
  const int dB = rem >> 6, hB = (rem >> 3) & 7, wB = rem & 7;
  const int dI = n >> 6, hI = (n >> 3) & 7, wI = n & 7;
  const int d = dB * 2 + dI, h = hB * 8 + hI, w = wB * 8 + wI;
  const int ds = (d + 1) & 7, hs = (h + 4) & 63, ws2 = (w + 4) & 63;
  return (((size_t)(b_ * 8 + ds) * 64 + hs) * 64 + ws2) * CC;
}

__device__ inline void ln120(float* xv, const float* __restrict__ g,
                             const float* __restrict__ bb) {
  float s0 = 0.f, s1 = 0.f, s2 = 0.f, s3 = 0.f;
#pragma unroll
  for (int k = 0; k < CC; k += 4) {
    s0 += xv[k]; s1 += xv[k + 1]; s2 += xv[k + 2]; s3 += xv[k + 3];
  }
  const float mean = ((s0 + s1) + (s2 + s3)) * (1.f / 120.f);
  float v0 = 0.f, v1 = 0.f, v2 = 0.f, v3 = 0.f;
#pragma unroll
  for (int k = 0; k < CC; k += 4) {
    float d0 = xv[k] - mean, d1 = xv[k + 1] - mean;
    float d2 = xv[k + 2] - mean, d3 = xv[k + 3] - mean;
    v0 += d0 * d0; v1 += d1 * d1; v2 += d2 * d2; v3 += d3 * d3;
  }
  const float rstd = rsqrtf(((v0 + v1) + (v2 + v3)) * (1.f / 120.f) + 1e-5f);
#pragma unroll
  for (int k = 0; k < CC; k++) xv[k] = (xv[k] - mean) * rstd * g[k] + bb[k];
}

__device__ inline float dot120(const float* xv, const float* __restrict__ wr) {
  float a0 = 0.f, a1 = 0.f, a2 = 0.f, a3 = 0.f;
#pragma unroll
  for (int k = 0; k < CC; k += 4) {
    a0 = fmaf(xv[k], wr[k], a0);
    a1 = fmaf(xv[k + 1], wr[k + 1], a1);
    a2 = fmaf(xv[k + 2], wr[k + 2], a2);
    a3 = fmaf(xv[k + 3], wr[k + 3], a3);
  }
  return (a0 + a1) + (a2 + a3);
}

// ---------------------------------------------------------------------------
// Self attention (fused LN + roll + partition + per-head QKV + attention).
// xstride = row stride of xout in bf16 elements (256 fast path, 240 fallback).
__global__ __launch_bounds__(128) void k_attn_self(
    const float* __restrict__ x, const float* __restrict__ g1,
    const float* __restrict__ b1, const float* __restrict__ wqkv,
    const float* __restrict__ bqkv, const float* __restrict__ mask,
    const float* __restrict__ rpb, const int* __restrict__ rpi,
    bf16* __restrict__ xout, int xstride) {
  __shared__ float kl[NTOK][HDIM];
  __shared__ float vl[NTOK][HDIM];
  const int wi = blockIdx.x, hh = blockIdx.y, t = threadIdx.x;
  const int token = wi * NTOK + t;
  const float* xr = x + token_src_offset(token);
  float xv[CC];
#pragma unroll
  for (int k = 0; k < CC; k++) xv[k] = xr[k];
  ln120(xv, g1, b1);
  float q[HDIM];
  for (int j = 0; j < HDIM; j++) {
    const int c = hh * HDIM + j;
    q[j] = (dot120(xv, wqkv + (size_t)c * CC) + bqkv[c]) * SCALE_F;
    kl[t][j] = dot120(xv, wqkv + (size_t)(CC + c) * CC) + bqkv[CC + c];
    vl[t][j] = dot120(xv, wqkv + (size_t)(2 * CC + c) * CC) + bqkv[2 * CC + c];
  }
  __syncthreads();
  const float* mrow = mask + ((size_t)(wi & 255) * NTOK + t) * NTOK;
  const int* rrow = rpi + t * NTOK;
  float sum = 0.f;
  float o[HDIM];
#pragma unroll
  for (int i = 0; i < HDIM; i++) o[i] = 0.f;
  for (int m = 0; m < NTOK; m++) {
    float a0 = 0.f, a1 = 0.f, a2 = 0.f, a3 = 0.f;
#pragma unroll
    for (int i = 0; i < HDIM; i += 4) {
      a0 = fmaf(q[i], kl[m][i], a0);
      a1 = fmaf(q[i + 1], kl[m][i + 1], a1);
      a2 = fmaf(q[i + 2], kl[m][i + 2], a2);
      a3 = fmaf(q[i + 3], kl[m][i + 3], a3);
    }
    const float sc = (a0 + a1) + (a2 + a3) + rpb[rrow[m] * NHEADS + hh] + mrow[m];
    const float p = __expf(sc);
    sum += p;
#pragma unroll
    for (int i = 0; i < HDIM; i++) o[i] = fmaf(p, vl[m][i], o[i]);
  }
  const float inv = 1.f / sum;
  bf16* orow = xout + (size_t)token * xstride + CC + hh * HDIM;
#pragma unroll
  for (int i = 0; i < HDIM; i++) orow[i] = __float2bfloat16(o[i] * inv);
}

// ---------------------------------------------------------------------------
// Mutual attention (fused). which=0: x1=attn(q2,k1,v1)->rows 0..63;
// which=1: x2=attn(q1,k2,v2)->rows 64..127.
__global__ __launch_bounds__(64) void k_attn_mut(
    const float* __restrict__ x, const float* __restrict__ g1,
    const float* __restrict__ b1, const float* __restrict__ wqkv,
    const float* __restrict__ bqkv, const float* __restrict__ pos,
    const float* __restrict__ mask, bf16* __restrict__ xout, int xstride) {
  __shared__ float kl[64][HDIM];
  __shared__ float vl[64][HDIM];
  const int wi = blockIdx.x, hh = blockIdx.y, which = blockIdx.z;
  const int t = threadIdx.x;
  const int qtok = which ? t : 64 + t;
  const int ktok = which ? 64 + t : t;
  const float* pr = pos + (size_t)t * CC;
  float xv[CC];
  {
    const float* xr = x + token_src_offset(wi * NTOK + ktok);
#pragma unroll
    for (int k = 0; k < CC; k++) xv[k] = xr[k];
    ln120(xv, g1, b1);
#pragma unroll
    for (int k = 0; k < CC; k++) xv[k] += pr[k];
    for (int j = 0; j < HDIM; j++) {
      const int c = hh * HDIM + j;
      kl[t][j] = dot120(xv, wqkv + (size_t)(CC + c) * CC) + bqkv[CC + c];
      vl[t][j] = dot120(xv, wqkv + (size_t)(2 * CC + c) * CC) + bqkv[2 * CC + c];
    }
  }
  float q[HDIM];
  {
    const float* xr = x + token_src_offset(wi * NTOK + qtok);
#pragma unroll
    for (int k = 0; k < CC; k++) xv[k] = xr[k];
    ln120(xv, g1, b1);
#pragma unroll
    for (int k = 0; k < CC; k++) xv[k] += pr[k];
    for (int j = 0; j < HDIM; j++) {
      const int c = hh * HDIM + j;
      q[j] = (dot120(xv, wqkv + (size_t)c * CC) + bqkv[c]) * SCALE_F;
    }
  }
  __syncthreads();
  const float* mrow = mask + ((size_t)(wi & 255) * NTOK + t) * NTOK;
  float sum = 0.f;
  float o[HDIM];
#pragma unroll
  for (int i = 0; i < HDIM; i++) o[i] = 0.f;
  for (int m = 0; m < 64; m++) {
    float a0 = 0.f, a1 = 0.f, a2 = 0.f, a3 = 0.f;
#pragma unroll
    for (int i = 0; i < HDIM; i += 4) {
      a0 = fmaf(q[i], kl[m][i], a0);
      a1 = fmaf(q[i + 1], kl[m][i + 1], a1);
      a2 = fmaf(q[i + 2], kl[m][i + 2], a2);
      a3 = fmaf(q[i + 3], kl[m][i + 3], a3);
    }
    const float p = __expf((a0 + a1) + (a2 + a3) + mrow[m]);
    sum += p;
#pragma unroll
    for (int i = 0; i < HDIM; i++) o[i] = fmaf(p, vl[m][i], o[i]);
  }
  const float inv = 1.f / sum;
  const int orow_i = which ? 64 + t : t;
  bf16* orow = xout + (size_t)(wi * NTOK + orow_i) * xstride + hh * HDIM;
#pragma unroll
  for (int i = 0; i < HDIM; i++) orow[i] = __float2bfloat16(o[i] * inv);
}

// ===========================================================================
// FAST PATH (MFMA)
// ===========================================================================
// Weight prep: cast fp32 weights to bf16, zero-padded K (so A-side pad may be
// garbage) and N. Layouts: Bffn [512][128] (rows 0..239=W11, 256..495=W12),
// Bfc2 [128][256], Bproj [128][256].
__global__ __launch_bounds__(256) void k_prep(
    const float* __restrict__ w11, const float* __restrict__ w12,
    const float* __restrict__ fc2w, const float* __restrict__ projw,
    bf16* __restrict__ Bffn, bf16* __restrict__ Bfc2, bf16* __restrict__ Bproj) {
  const int i = blockIdx.x * 256 + threadIdx.x;
  if (i < 65536) {
    const int r = i >> 7, k = i & 127;
    float v = 0.f;
    if (k < 120) {
      if (r < 240) v = w11[r * 120 + k];
      else if (r >= 256 && r < 496) v = w12[(r - 256) * 120 + k];
    }
    Bffn[i] = __float2bfloat16(v);
  } else if (i < 98304) {
    const int j = i - 65536, r = j >> 8, k = j & 255;
    Bfc2[j] = __float2bfloat16((r < 120 && k < 240) ? fc2w[r * 240 + k] : 0.f);
  } else if (i < 131072) {
    const int j = i - 98304, r = j >> 8, k = j & 255;
    Bproj[j] = __float2bfloat16((r < 120 && k < 240) ? projw[r * 240 + k] : 0.f);
  }
}

// LN2 -> bf16 A-matrix [131072][128] (cols 120..127 left as-is; B pad is 0).
__global__ __launch_bounds__(256) void k_ln2(
    const float* __restrict__ out, const float* __restrict__ g2,
    const float* __restrict__ b2, bf16* __restrict__ A2) {
  const int row = blockIdx.x * 256 + threadIdx.x;
  const float* xr = out + (size_t)row * CC;
  float xv[CC];
#pragma unroll
  for (int k = 0; k < CC; k++) xv[k] = xr[k];
  ln120(xv, g2, b2);
  __hip_bfloat162* dst = (__hip_bfloat162*)(A2 + (size_t)row * 128);
#pragma unroll
  for (int k = 0; k < CC; k += 2) {
    __hip_bfloat162 p;
    p.x = __float2bfloat16(xv[k]);
    p.y = __float2bfloat16(xv[k + 1]);
    dst[k >> 1] = p;
  }
}

// FFN1 MFMA: h = gelu(A2@W11^T) * (A2@W12^T). Wave owns n-tile pair (j, j+16)
// of Bffn (same output cols of W11/W12). B frags in regs; A frags from global.
__global__ __launch_bounds__(256) void k_ffn1_mfma(
    const bf16* __restrict__ A2, const bf16* __restrict__ Bffn,
    const float* __restrict__ b11, const float* __restrict__ b12,
    bf16* __restrict__ h) {
  const int j = blockIdx.x * 4 + (threadIdx.x >> 6);  // pair index 0..15
  const int lane = threadIdx.x & 63;
  const int ln = lane & 15, quad = lane >> 4;
  bf16x8 b1f[4], b2f[4];
#pragma unroll
  for (int s = 0; s < 4; s++) {
    b1f[s] = *(const bf16x8*)(Bffn + (size_t)(j * 16 + ln) * 128 + s * 32 + quad * 8);
    b2f[s] = *(const bf16x8*)(Bffn + (size_t)(j * 16 + 256 + ln) * 128 + s * 32 + quad * 8);
  }
  const int col = j * 16 + ln;
  const float bias1 = (col < HID2) ? b11[col] : 0.f;
  const float bias2 = (col < HID2) ? b12[col] : 0.f;
  const int m_base = blockIdx.y * 512;
  for (int it = 0; it < 16; it++) {
    const int m0 = m_base + it * 32;
    f32x4 acc[2][2] = {};
    bf16x8 af[2][4];
#pragma unroll
    for (int mi = 0; mi < 2; mi++)
#pragma unroll
      for (int s = 0; s < 4; s++)
        af[mi][s] = *(const bf16x8*)(A2 + (size_t)(m0 + mi * 16 + ln) * 128 + s * 32 + quad * 8);
#pragma unroll
    for (int s = 0; s < 4; s++)
#pragma unroll
      for (int mi = 0; mi < 2; mi++) {
        acc[mi][0] = mfma16(af[mi][s], b1f[s], acc[mi][0]);
        acc[mi][1] = mfma16(af[mi][s], b2f[s], acc[mi][1]);
      }
    if (col < HID2) {
#pragma unroll
      for (int mi = 0; mi < 2; mi++)
#pragma unroll
        for (int r = 0; r < 4; r++) {
          const int row = m0 + mi * 16 + quad * 4 + r;
          const float a = acc[mi][0][r] + bias1;
          const float c = acc[mi][1][r] + bias2;
          const float ge = 0.5f * a * (1.f + erff(a * 0.70710678118654752f));
          h[(size_t)row * 256 + col] = __float2bfloat16(ge * c);
        }
    }
  }
}

// Output GEMMs, K=256 (padded), N=120 (8 n-tiles, last half-masked).
// PROJ: out[dst+col] = x[dst+col] + pb[col] + acc   (scatter via token map)
// else: out[row*120+col] += b2[col] + acc           (FFN2 accumulate)
template <bool PROJ>
__global__ __launch_bounds__(256) void k_out_mfma(
    const bf16* __restrict__ A, const bf16* __restrict__ Bw,
    const float* __restrict__ bias, const float* __restrict__ xin,
    float* __restrict__ out) {
  const int w = threadIdx.x >> 6;  // wave 0..3 owns n-tiles 2w, 2w+1
  const int lane = threadIdx.x & 63;
  const int ln = lane & 15, quad = lane >> 4;
  bf16x8 bf[2][8];
#pragma unroll
  for (int nt = 0; nt < 2; nt++)
#pragma unroll
    for (int s = 0; s < 8; s++)
      bf[nt][s] = *(const bf16x8*)(Bw + (size_t)((w * 2 + nt) * 16 + ln) * 256 + s * 32 + quad * 8);
  const int m_base = blockIdx.y * 256;
  for (int it = 0; it < 8; it++) {
    const int m0 = m_base + it * 32;
    f32x4 acc[2][2] = {};
    bf16x8 af[2][8];
#pragma unroll
    for (int mi = 0; mi < 2; mi++)
#pragma unroll
      for (int s = 0; s < 8; s++)
        af[mi][s] = *(const bf16x8*)(A + (size_t)(m0 + mi * 16 + ln) * 256 + s * 32 + quad * 8);
#pragma unroll
    for (int s = 0; s < 8; s++)
#pragma unroll
      for (int mi = 0; mi < 2; mi++)
#pragma unroll
        for (int nt = 0; nt < 2; nt++)
          acc[mi][nt] = mfma16(af[mi][s], bf[nt][s], acc[mi][nt]);
#pragma unroll
    for (int mi = 0; mi < 2; mi++)
#pragma unroll
      for (int nt = 0; nt < 2; nt++) {
        const int colc = (w * 2 + nt) * 16 + ln;
        if (colc < CC) {
#pragma unroll
          for (int r = 0; r < 4; r++) {
            const int row = m0 + mi * 16 + quad * 4 + r;
            if (PROJ) {
              const size_t dst = token_src_offset(row);
              out[dst + colc] = xin[dst + colc] + bias[colc] + acc[mi][nt][r];
            } else {
              out[(size_t)row * CC + colc] += bias[colc] + acc[mi][nt][r];
            }
          }
        }
      }
  }
}

// ===========================================================================
// FALLBACK PATH (round-2 VALU kernels, xout stride 240)
// ===========================================================================
template <int HALF>
__global__ __launch_bounds__(256) void k_proj_fb(
    const bf16* __restrict__ xout, const float* __restrict__ pw,
    const float* __restrict__ pb, const float* __restrict__ xin,
    float* __restrict__ out) {
  const int token = blockIdx.x * 256 + threadIdx.x;
  float xv[CC];
  const bf16* xr = xout + (size_t)token * HID2 + HALF * CC;
#pragma unroll
  for (int k = 0; k < CC; k++) xv[k] = __bfloat162float(xr[k]);
  const size_t dst = token_src_offset(token);
  for (int o = 0; o < CC; o++) {
    const float acc = dot120(xv, pw + (size_t)o * HID2 + HALF * CC);
    if (HALF == 0)
      out[dst + o] = xin[dst + o] + pb[o] + acc;
    else
      out[dst + o] += acc;
  }
}

__global__ __launch_bounds__(256) void k_ffn1_fb(
    const float* __restrict__ xres, const float* __restrict__ g,
    const float* __restrict__ bb, const float* __restrict__ w11,
    const float* __restrict__ b11, const float* __restrict__ w12,
    const float* __restrict__ b12, bf16* __restrict__ hbuf) {
  const int row = blockIdx.x * 256 + threadIdx.x;
  const float* xr = xres + (size_t)row * CC;
  float xv[CC];
#pragma unroll
  for (int k = 0; k < CC; k++) xv[k] = xr[k];
  ln120(xv, g, bb);
  bf16* hr = hbuf + (size_t)row * HID2;
  for (int o = 0; o < HID2; o++) {
    const float a = b11[o] + dot120(xv, w11 + (size_t)o * CC);
    const float c = b12[o] + dot120(xv, w12 + (size_t)o * CC);
    const float ge = 0.5f * a * (1.f + erff(a * 0.70710678118654752f));
    hr[o] = __float2bfloat16(ge * c);
  }
}

template <int HALF>
__global__ __launch_bounds__(256) void k_ffn2_fb(
    const bf16* __restrict__ hbuf, const float* __restrict__ w2,
    const float* __restrict__ b2f, float* __restrict__ out) {
  const int row = blockIdx.x * 256 + threadIdx.x;
  float xv[CC];
  const bf16* xr = hbuf + (size_t)row * HID2 + HALF * CC;
#pragma unroll
  for (int k = 0; k < CC; k++) xv[k] = __bfloat162float(xr[k]);
  float* orow = out + (size_t)row * CC;
  for (int o = 0; o < CC; o++) {
    float acc = dot120(xv, w2 + (size_t)o * HID2 + HALF * CC);
    if (HALF == 0) acc += b2f[o];
    orow[o] += acc;
  }
}

// ---------------------------------------------------------------------------
extern "C" void kernel_launch(void* const* d_in, const int* in_sizes, int n_in,
                              void* d_out, int out_size, void* d_ws, size_t ws_size,
                              hipStream_t stream) {
  const float* x          = (const float*)d_in[0];
  const float* attn_mask  = (const float*)d_in[1];
  const float* g1         = (const float*)d_in[2];
  const float* b1         = (const float*)d_in[3];
  const float* qkv_self_w = (const float*)d_in[4];
  const float* qkv_self_b = (const float*)d_in[5];
  const float* qkv_mut_w  = (const float*)d_in[6];
  const float* qkv_mut_b  = (const float*)d_in[7];
  const float* proj_w     = (const float*)d_in[8];
  const float* proj_b     = (const float*)d_in[9];
  const float* rpb_table  = (const float*)d_in[10];
  const float* pos_bias   = (const float*)d_in[11];
  const float* g2         = (const float*)d_in[12];
  const float* b2         = (const float*)d_in[13];
  const float* fc11_w     = (const float*)d_in[14];
  const float* fc11_b     = (const float*)d_in[15];
  const float* fc12_w     = (const float*)d_in[16];
  const float* fc12_b     = (const float*)d_in[17];
  const float* fc2_w      = (const float*)d_in[18];
  const float* fc2_b      = (const float*)d_in[19];
  const int*   rpi        = (const int*)d_in[20];
  float* out = (float*)d_out;

  // Fast-path workspace layout (bytes):
  //   xout/h : 131072*256*2 = 67,108,864   (attention concat, reused as FFN hidden)
  //   A2     : 131072*128*2 = 33,554,432   (LN2 output, K-padded)
  //   Bffn   : 512*128*2    =    131,072
  //   Bfc2   : 128*256*2    =     65,536
  //   Bproj  : 128*256*2    =     65,536   -> total 100,925,440
  const bool fast = ws_size >= (size_t)100925440;

  if (fast) {
    bf16* xout  = (bf16*)d_ws;
    bf16* hbuf  = xout;  // reused after proj consumes xout
    bf16* A2    = (bf16*)((char*)d_ws + 67108864);
    bf16* Bffn  = (bf16*)((char*)d_ws + 100663296);
    bf16* Bfc2  = Bffn + 65536;
    bf16* Bproj = Bfc2 + 32768;

    k_prep<<<512, 256, 0, stream>>>(fc11_w, fc12_w, fc2_w, proj_w, Bffn, Bfc2, Bproj);
    k_attn_self<<<dim3(1024, NHEADS), 128, 0, stream>>>(
        x, g1, b1, qkv_self_w, qkv_self_b, attn_mask, rpb_table, rpi, xout, 256);
    k_attn_mut<<<dim3(1024, NHEADS, 2), 64, 0, stream>>>(
        x, g1, b1, qkv_mut_w, qkv_mut_b, pos_bias, attn_mask, xout, 256);
    k_out_mfma<true><<<dim3(1, 512), 256, 0, stream>>>(xout, Bproj, proj_b, x, out);
    k_ln2<<<512, 256, 0, stream>>>(out, g2, b2, A2);
    k_ffn1_mfma<<<dim3(4, 256), 256, 0, stream>>>(A2, Bffn, fc11_b, fc12_b, hbuf);
    k_out_mfma<false><<<dim3(1, 512), 256, 0, stream>>>(hbuf, Bfc2, fc2_b, nullptr, out);
  } else {
    bf16* xout = (bf16*)d_ws;
    bf16* hbuf = (bf16*)d_ws;
    k_attn_self<<<dim3(1024, NHEADS), 128, 0, stream>>>(
        x, g1, b1, qkv_self_w, qkv_self_b, attn_mask, rpb_table, rpi, xout, 240);
    k_attn_mut<<<dim3(1024, NHEADS, 2), 64, 0, stream>>>(
        x, g1, b1, qkv_mut_w, qkv_mut_b, pos_bias, attn_mask, xout, 240);
    k_proj_fb<0><<<512, 256, 0, stream>>>(xout, proj_w, proj_b, x, out);
    k_proj_fb<1><<<512, 256, 0, stream>>>(xout, proj_w, proj_b, x, out);
    k_ffn1_fb<<<512, 256, 0, stream>>>(out, g2, b2, fc11_w, fc11_b, fc12_w, fc12_b, hbuf);
    k_ffn2_fb<0><<<512, 256, 0, stream>>>(hbuf, fc2_w, fc2_b, out);
    k_ffn2_fb<1><<<512, 256, 0, stream>>>(hbuf, fc2_w, fc2_b, out);
  }
}

// Round 4
// 973.000 us; speedup vs baseline: 6.1283x; 2.5347x over previous
//
#include <hip/hip_runtime.h>
#include <hip/hip_bf16.h>
#include <math.h>

#define CC 120       // channels
#define NHEADS 6
#define HDIM 20      // head dim
#define NTOK 128     // tokens per window
#define HID2 240
#define SCALE_F 0.2236067977499790f  // 20^-0.5

typedef __hip_bfloat16 bf16;
typedef __attribute__((ext_vector_type(8))) short bf16x8;   // 8 bf16 (4 VGPRs)
typedef __attribute__((ext_vector_type(4))) float f32x4;    // MFMA accumulator

__device__ inline f32x4 mfma16(bf16x8 a, bf16x8 b, f32x4 c) {
  return __builtin_amdgcn_mfma_f32_16x16x32_bf16(a, b, c, 0, 0, 0);
}

// ---------------------------------------------------------------------------
// token -> rolled spatial source position (also the scatter destination for
// window-reverse + un-roll, which is the same map).
__device__ inline size_t token_src_offset(int token) {
  const int wi = token >> 7, n = token & 127;
  const int b_ = wi >> 8, rem = wi & 255;
  const int dB = rem >> 6, hB = (rem >> 3) & 7, wB = rem & 7;
  const int dI = n >> 6, hI = (n >> 3) & 7, wI = n & 7;
  const int d = dB * 2 + dI, h = hB * 8 + hI, w = wB * 8 + wI;
  const int ds = (d + 1) & 7, hs = (h + 4) & 63, ws2 = (w + 4) & 63;
  return (((size_t)(b_ * 8 + ds) * 64 + hs) * 64 + ws2) * CC;
}

__device__ inline void ln120(float* xv, const float* __restrict__ g,
                             const float* __restrict__ bb) {
  float s0 = 0.f, s1 = 0.f, s2 = 0.f, s3 = 0.f;
#pragma unroll
  for (int k = 0; k < CC; k += 4) {
    s0 += xv[k]; s1 += xv[k + 1]; s2 += xv[k + 2]; s3 += xv[k + 3];
  }
  const float mean = ((s0 + s1) + (s2 + s3)) * (1.f / 120.f);
  float v0 = 0.f, v1 = 0.f, v2 = 0.f, v3 = 0.f;
#pragma unroll
  for (int k = 0; k < CC; k += 4) {
    float d0 = xv[k] - mean, d1 = xv[k + 1] - mean;
    float d2 = xv[k + 2] - mean, d3 = xv[k + 3] - mean;
    v0 += d0 * d0; v1 += d1 * d1; v2 += d2 * d2; v3 += d3 * d3;
  }
  const float rstd = rsqrtf(((v0 + v1) + (v2 + v3)) * (1.f / 120.f) + 1e-5f);
#pragma unroll
  for (int k = 0; k < CC; k++) xv[k] = (xv[k] - mean) * rstd * g[k] + bb[k];
}

__device__ inline float dot120(const float* xv, const float* __restrict__ wr) {
  float a0 = 0.f, a1 = 0.f, a2 = 0.f, a3 = 0.f;
#pragma unroll
  for (int k = 0; k < CC; k += 4) {
    a0 = fmaf(xv[k], wr[k], a0);
    a1 = fmaf(xv[k + 1], wr[k + 1], a1);
    a2 = fmaf(xv[k + 2], wr[k + 2], a2);
    a3 = fmaf(xv[k + 3], wr[k + 3], a3);
  }
  return (a0 + a1) + (a2 + a3);
}

// ===========================================================================
// FAST PATH
// ===========================================================================
// Weight prep. Bffn [512][128] (rows 0..239 = W11, 256..495 = W12),
// Bfc2 [128][256], Bproj [128][256],
// Wself/Wmut [384][128]: rows 0..127=q (SCALE folded), 128..255=k, 256..383=v;
// col 120 holds the bias (A1 col 120 == 1.0), cols 121..127 = 0.
__global__ __launch_bounds__(256) void k_prep(
    const float* __restrict__ w11, const float* __restrict__ w12,
    const float* __restrict__ fc2w, const float* __restrict__ projw,
    const float* __restrict__ wself, const float* __restrict__ bself,
    const float* __restrict__ wmut, const float* __restrict__ bmut,
    bf16* __restrict__ Bffn, bf16* __restrict__ Bfc2, bf16* __restrict__ Bproj,
    bf16* __restrict__ Wself, bf16* __restrict__ Wmut) {
  const int i = blockIdx.x * 256 + threadIdx.x;
  if (i < 65536) {
    const int r = i >> 7, k = i & 127;
    float v = 0.f;
    if (k < 120) {
      if (r < 240) v = w11[r * 120 + k];
      else if (r >= 256 && r < 496) v = w12[(r - 256) * 120 + k];
    }
    Bffn[i] = __float2bfloat16(v);
  } else if (i < 98304) {
    const int j = i - 65536, r = j >> 8, k = j & 255;
    Bfc2[j] = __float2bfloat16((r < 120 && k < 240) ? fc2w[r * 240 + k] : 0.f);
  } else if (i < 131072) {
    const int j = i - 98304, r = j >> 8, k = j & 255;
    Bproj[j] = __float2bfloat16((r < 120 && k < 240) ? projw[r * 240 + k] : 0.f);
  } else if (i < 229376) {
    const int j = (i - 131072) % 49152;
    const bool is_self = (i - 131072) < 49152;
    const float* w = is_self ? wself : wmut;
    const float* b = is_self ? bself : bmut;
    const int r = j >> 7, k = j & 127;
    float v = 0.f;
    const int grp = r >> 7;          // 0=q 1=k 2=v
    const int rr = r & 127;
    if (rr < 120) {
      const int orow = grp * 120 + rr;
      if (k < 120) v = w[orow * 120 + k];
      else if (k == 120) v = b[orow];
      if (grp == 0) v *= SCALE_F;
    }
    (is_self ? Wself : Wmut)[j] = __float2bfloat16(v);
  }
}

// posq[t63][c] = dot(pos[t63], Wmut_orig[c]) (SCALE on q cols, no bias). fp32.
__global__ __launch_bounds__(256) void k_posq(
    const float* __restrict__ pos, const float* __restrict__ wmut,
    float* __restrict__ posq) {
  const int i = blockIdx.x * 256 + threadIdx.x;
  if (i >= 64 * 384) return;
  const int t63 = i / 384, c = i % 384;
  const int grp = c >> 7, rr = c & 127;
  float v = 0.f;
  if (rr < 120) {
    v = dot120(pos + (size_t)t63 * CC, wmut + (size_t)(grp * 120 + rr) * CC);
    if (grp == 0) v *= SCALE_F;
  }
  posq[i] = v;
}

// LN1 + roll + partition -> A1 bf16 [131072][128], col 120 = 1.0 (bias col).
__global__ __launch_bounds__(256) void k_a1(
    const float* __restrict__ x, const float* __restrict__ g1,
    const float* __restrict__ b1, bf16* __restrict__ A1) {
  const int token = blockIdx.x * 256 + threadIdx.x;
  const float* xr = x + token_src_offset(token);
  float xv[CC];
#pragma unroll
  for (int k = 0; k < CC; k++) xv[k] = xr[k];
  ln120(xv, g1, b1);
  __hip_bfloat162* dst = (__hip_bfloat162*)(A1 + (size_t)token * 128);
#pragma unroll
  for (int k = 0; k < CC; k += 2) {
    __hip_bfloat162 p;
    p.x = __float2bfloat16(xv[k]);
    p.y = __float2bfloat16(xv[k + 1]);
    dst[k >> 1] = p;
  }
  __hip_bfloat162 pad1; pad1.x = __float2bfloat16(1.f); pad1.y = __float2bfloat16(0.f);
  __hip_bfloat162 pad0; pad0.x = pad0.y = __float2bfloat16(0.f);
  dst[60] = pad1; dst[61] = pad0; dst[62] = pad0; dst[63] = pad0;
}

// QKV GEMM: qkv[row][c] = A1[hbase+row] . W[c]  (+ posq[row&63][c] if MUT).
// K=128, N=384 (24 tiles -> 12 pairs -> grid.x=3, 4 waves/block).
template <bool MUT>
__global__ __launch_bounds__(256) void k_qkv_mfma(
    const bf16* __restrict__ A1, const bf16* __restrict__ W,
    const float* __restrict__ posq, bf16* __restrict__ qkv, int hbase) {
  const int wv = threadIdx.x >> 6;
  const int pair = blockIdx.x * 4 + wv;  // 0..11
  const int lane = threadIdx.x & 63;
  const int ln = lane & 15, quad = lane >> 4;
  bf16x8 bfr[2][4];
#pragma unroll
  for (int nt = 0; nt < 2; nt++)
#pragma unroll
    for (int s = 0; s < 4; s++)
      bfr[nt][s] = *(const bf16x8*)(W + (size_t)((pair * 2 + nt) * 16 + ln) * 128 + s * 32 + quad * 8);
  const int m_base = blockIdx.y * 128;
  for (int it = 0; it < 4; it++) {
    const int m0 = m_base + it * 32;
    f32x4 acc[2][2] = {};
    bf16x8 af[2][4];
#pragma unroll
    for (int mi = 0; mi < 2; mi++)
#pragma unroll
      for (int s = 0; s < 4; s++)
        af[mi][s] = *(const bf16x8*)(A1 + (size_t)(hbase + m0 + mi * 16 + ln) * 128 + s * 32 + quad * 8);
#pragma unroll
    for (int s = 0; s < 4; s++)
#pragma unroll
      for (int mi = 0; mi < 2; mi++)
#pragma unroll
        for (int nt = 0; nt < 2; nt++)
          acc[mi][nt] = mfma16(af[mi][s], bfr[nt][s], acc[mi][nt]);
#pragma unroll
    for (int mi = 0; mi < 2; mi++)
#pragma unroll
      for (int nt = 0; nt < 2; nt++) {
        const int col = (pair * 2 + nt) * 16 + ln;
#pragma unroll
        for (int r = 0; r < 4; r++) {
          const int row = m0 + mi * 16 + quad * 4 + r;
          float v = acc[mi][nt][r];
          if (MUT) v += posq[(row & 63) * 384 + col];
          qkv[(size_t)row * 384 + col] = __float2bfloat16(v);
        }
      }
  }
}

// Self attention core: block (window-in-half, head), thread = query token.
// qkv rows local to half; layout cols 0..119 q, 128..247 k, 256..375 v.
__global__ __launch_bounds__(128) void k_attn_self2(
    const bf16* __restrict__ qkv, const float* __restrict__ mask,
    const float* __restrict__ rpb, const int* __restrict__ rpi,
    bf16* __restrict__ xout, int wbase) {
  __shared__ float kl[NTOK][HDIM];
  __shared__ float vl[NTOK][HDIM];
  const int wiL = blockIdx.x, hh = blockIdx.y, t = threadIdx.x;
  const int wi = wbase + wiL;
  const bf16* base = qkv + (size_t)wiL * NTOK * 384;
  for (int e = t; e < NTOK * HDIM; e += 128) {
    const int m = e / HDIM, j = e - m * HDIM;
    kl[m][j] = __bfloat162float(base[(size_t)m * 384 + 128 + hh * HDIM + j]);
    vl[m][j] = __bfloat162float(base[(size_t)m * 384 + 256 + hh * HDIM + j]);
  }
  __syncthreads();
  float q[HDIM];
#pragma unroll
  for (int j = 0; j < HDIM; j++)
    q[j] = __bfloat162float(base[(size_t)t * 384 + hh * HDIM + j]);
  const float* mrow = mask + ((size_t)(wi & 255) * NTOK + t) * NTOK;
  const int* rrow = rpi + t * NTOK;
  float sum = 0.f;
  float o[HDIM];
#pragma unroll
  for (int i = 0; i < HDIM; i++) o[i] = 0.f;
  for (int m = 0; m < NTOK; m++) {
    float a0 = 0.f, a1 = 0.f, a2 = 0.f, a3 = 0.f;
#pragma unroll
    for (int i = 0; i < HDIM; i += 4) {
      a0 = fmaf(q[i], kl[m][i], a0);
      a1 = fmaf(q[i + 1], kl[m][i + 1], a1);
      a2 = fmaf(q[i + 2], kl[m][i + 2], a2);
      a3 = fmaf(q[i + 3], kl[m][i + 3], a3);
    }
    const float sc = (a0 + a1) + (a2 + a3) + rpb[rrow[m] * NHEADS + hh] + mrow[m];
    const float p = __expf(sc);
    sum += p;
#pragma unroll
    for (int i = 0; i < HDIM; i++) o[i] = fmaf(p, vl[m][i], o[i]);
  }
  const float inv = 1.f / sum;
  bf16* orow = xout + (size_t)(wi * NTOK + t) * 256 + CC + hh * HDIM;
#pragma unroll
  for (int i = 0; i < HDIM; i++) orow[i] = __float2bfloat16(o[i] * inv);
}

// Mutual attention core: block (window-in-half, head), 128 threads.
// t<64  (grp0): q = row 64+t, keys 0..63,   out row t     (x1)
// t>=64 (grp1): q = row t-64, keys 64..127, out row 64+tt (x2)
__global__ __launch_bounds__(128) void k_attn_mut2(
    const bf16* __restrict__ qkv, const float* __restrict__ mask,
    bf16* __restrict__ xout, int wbase) {
  __shared__ float kl[NTOK][HDIM];
  __shared__ float vl[NTOK][HDIM];
  const int wiL = blockIdx.x, hh = blockIdx.y, t = threadIdx.x;
  const int wi = wbase + wiL;
  const int grp = t >> 6, tt = t & 63;
  const bf16* base = qkv + (size_t)wiL * NTOK * 384;
  for (int e = t; e < NTOK * HDIM; e += 128) {
    const int m = e / HDIM, j = e - m * HDIM;
    kl[m][j] = __bfloat162float(base[(size_t)m * 384 + 128 + hh * HDIM + j]);
    vl[m][j] = __bfloat162float(base[(size_t)m * 384 + 256 + hh * HDIM + j]);
  }
  __syncthreads();
  const int qr = grp ? tt : 64 + tt;
  const int kb = grp ? 64 : 0;
  float q[HDIM];
#pragma unroll
  for (int j = 0; j < HDIM; j++)
    q[j] = __bfloat162float(base[(size_t)qr * 384 + hh * HDIM + j]);
  const float* mrow = mask + ((size_t)(wi & 255) * NTOK + tt) * NTOK;
  float sum = 0.f;
  float o[HDIM];
#pragma unroll
  for (int i = 0; i < HDIM; i++) o[i] = 0.f;
  for (int m = 0; m < 64; m++) {
    const int km = kb + m;
    float a0 = 0.f, a1 = 0.f, a2 = 0.f, a3 = 0.f;
#pragma unroll
    for (int i = 0; i < HDIM; i += 4) {
      a0 = fmaf(q[i], kl[km][i], a0);
      a1 = fmaf(q[i + 1], kl[km][i + 1], a1);
      a2 = fmaf(q[i + 2], kl[km][i + 2], a2);
      a3 = fmaf(q[i + 3], kl[km][i + 3], a3);
    }
    const float p = __expf((a0 + a1) + (a2 + a3) + mrow[m]);
    sum += p;
#pragma unroll
    for (int i = 0; i < HDIM; i++) o[i] = fmaf(p, vl[km][i], o[i]);
  }
  const float inv = 1.f / sum;
  const int orow_i = grp ? 64 + tt : tt;
  bf16* orow = xout + (size_t)(wi * NTOK + orow_i) * 256 + hh * HDIM;
#pragma unroll
  for (int i = 0; i < HDIM; i++) orow[i] = __float2bfloat16(o[i] * inv);
}

// LN2 -> bf16 A-matrix [131072][128] (B pad rows are 0, A pad may be garbage).
__global__ __launch_bounds__(256) void k_ln2(
    const float* __restrict__ out, const float* __restrict__ g2,
    const float* __restrict__ b2, bf16* __restrict__ A2) {
  const int row = blockIdx.x * 256 + threadIdx.x;
  const float* xr = out + (size_t)row * CC;
  float xv[CC];
#pragma unroll
  for (int k = 0; k < CC; k++) xv[k] = xr[k];
  ln120(xv, g2, b2);
  __hip_bfloat162* dst = (__hip_bfloat162*)(A2 + (size_t)row * 128);
#pragma unroll
  for (int k = 0; k < CC; k += 2) {
    __hip_bfloat162 p;
    p.x = __float2bfloat16(xv[k]);
    p.y = __float2bfloat16(xv[k + 1]);
    dst[k >> 1] = p;
  }
}

// FFN1 MFMA: h = gelu(A2@W11^T) * (A2@W12^T).
__global__ __launch_bounds__(256) void k_ffn1_mfma(
    const bf16* __restrict__ A2, const bf16* __restrict__ Bffn,
    const float* __restrict__ b11, const float* __restrict__ b12,
    bf16* __restrict__ h) {
  const int j = blockIdx.x * 4 + (threadIdx.x >> 6);  // pair index 0..15
  const int lane = threadIdx.x & 63;
  const int ln = lane & 15, quad = lane >> 4;
  bf16x8 b1f[4], b2f[4];
#pragma unroll
  for (int s = 0; s < 4; s++) {
    b1f[s] = *(const bf16x8*)(Bffn + (size_t)(j * 16 + ln) * 128 + s * 32 + quad * 8);
    b2f[s] = *(const bf16x8*)(Bffn + (size_t)(j * 16 + 256 + ln) * 128 + s * 32 + quad * 8);
  }
  const int col = j * 16 + ln;
  const float bias1 = (col < HID2) ? b11[col] : 0.f;
  const float bias2 = (col < HID2) ? b12[col] : 0.f;
  const int m_base = blockIdx.y * 512;
  for (int it = 0; it < 16; it++) {
    const int m0 = m_base + it * 32;
    f32x4 acc[2][2] = {};
    bf16x8 af[2][4];
#pragma unroll
    for (int mi = 0; mi < 2; mi++)
#pragma unroll
      for (int s = 0; s < 4; s++)
        af[mi][s] = *(const bf16x8*)(A2 + (size_t)(m0 + mi * 16 + ln) * 128 + s * 32 + quad * 8);
#pragma unroll
    for (int s = 0; s < 4; s++)
#pragma unroll
      for (int mi = 0; mi < 2; mi++) {
        acc[mi][0] = mfma16(af[mi][s], b1f[s], acc[mi][0]);
        acc[mi][1] = mfma16(af[mi][s], b2f[s], acc[mi][1]);
      }
    if (col < HID2) {
#pragma unroll
      for (int mi = 0; mi < 2; mi++)
#pragma unroll
        for (int r = 0; r < 4; r++) {
          const int row = m0 + mi * 16 + quad * 4 + r;
          const float a = acc[mi][0][r] + bias1;
          const float c = acc[mi][1][r] + bias2;
          const float ge = 0.5f * a * (1.f + erff(a * 0.70710678118654752f));
          h[(size_t)row * 256 + col] = __float2bfloat16(ge * c);
        }
    }
  }
}

// Output GEMMs, K=256 (padded), N=120.
template <bool PROJ>
__global__ __launch_bounds__(256) void k_out_mfma(
    const bf16* __restrict__ A, const bf16* __restrict__ Bw,
    const float* __restrict__ bias, const float* __restrict__ xin,
    float* __restrict__ out) {
  const int w = threadIdx.x >> 6;
  const int lane = threadIdx.x & 63;
  const int ln = lane & 15, quad = lane >> 4;
  bf16x8 bfr[2][8];
#pragma unroll
  for (int nt = 0; nt < 2; nt++)
#pragma unroll
    for (int s = 0; s < 8; s++)
      bfr[nt][s] = *(const bf16x8*)(Bw + (size_t)((w * 2 + nt) * 16 + ln) * 256 + s * 32 + quad * 8);
  const int m_base = blockIdx.y * 256;
  for (int it = 0; it < 8; it++) {
    const int m0 = m_base + it * 32;
    f32x4 acc[2][2] = {};
    bf16x8 af[2][8];
#pragma unroll
    for (int mi = 0; mi < 2; mi++)
#pragma unroll
      for (int s = 0; s < 8; s++)
        af[mi][s] = *(const bf16x8*)(A + (size_t)(m0 + mi * 16 + ln) * 256 + s * 32 + quad * 8);
#pragma unroll
    for (int s = 0; s < 8; s++)
#pragma unroll
      for (int mi = 0; mi < 2; mi++)
#pragma unroll
        for (int nt = 0; nt < 2; nt++)
          acc[mi][nt] = mfma16(af[mi][s], bfr[nt][s], acc[mi][nt]);
#pragma unroll
    for (int mi = 0; mi < 2; mi++)
#pragma unroll
      for (int nt = 0; nt < 2; nt++) {
        const int colc = (w * 2 + nt) * 16 + ln;
        if (colc < CC) {
#pragma unroll
          for (int r = 0; r < 4; r++) {
            const int row = m0 + mi * 16 + quad * 4 + r;
            if (PROJ) {
              const size_t dst = token_src_offset(row);
              out[dst + colc] = xin[dst + colc] + bias[colc] + acc[mi][nt][r];
            } else {
              out[(size_t)row * CC + colc] += bias[colc] + acc[mi][nt][r];
            }
          }
        }
      }
  }
}

// ===========================================================================
// FALLBACK PATH (round-2 proven kernels; used only if ws is too small)
// ===========================================================================
__global__ __launch_bounds__(128) void k_attn_self_fb(
    const float* __restrict__ x, const float* __restrict__ g1,
    const float* __restrict__ b1, const float* __restrict__ wqkv,
    const float* __restrict__ bqkv, const float* __restrict__ mask,
    const float* __restrict__ rpb, const int* __restrict__ rpi,
    bf16* __restrict__ xout) {
  __shared__ float kl[NTOK][HDIM];
  __shared__ float vl[NTOK][HDIM];
  const int wi = blockIdx.x, hh = blockIdx.y, t = threadIdx.x;
  const int token = wi * NTOK + t;
  const float* xr = x + token_src_offset(token);
  float xv[CC];
#pragma unroll
  for (int k = 0; k < CC; k++) xv[k] = xr[k];
  ln120(xv, g1, b1);
  float q[HDIM];
  for (int j = 0; j < HDIM; j++) {
    const int c = hh * HDIM + j;
    q[j] = (dot120(xv, wqkv + (size_t)c * CC) + bqkv[c]) * SCALE_F;
    kl[t][j] = dot120(xv, wqkv + (size_t)(CC + c) * CC) + bqkv[CC + c];
    vl[t][j] = dot120(xv, wqkv + (size_t)(2 * CC + c) * CC) + bqkv[2 * CC + c];
  }
  __syncthreads();
  const float* mrow = mask + ((size_t)(wi & 255) * NTOK + t) * NTOK;
  const int* rrow = rpi + t * NTOK;
  float sum = 0.f;
  float o[HDIM];
#pragma unroll
  for (int i = 0; i < HDIM; i++) o[i] = 0.f;
  for (int m = 0; m < NTOK; m++) {
    float a0 = 0.f, a1 = 0.f, a2 = 0.f, a3 = 0.f;
#pragma unroll
    for (int i = 0; i < HDIM; i += 4) {
      a0 = fmaf(q[i], kl[m][i], a0);
      a1 = fmaf(q[i + 1], kl[m][i + 1], a1);
      a2 = fmaf(q[i + 2], kl[m][i + 2], a2);
      a3 = fmaf(q[i + 3], kl[m][i + 3], a3);
    }
    const float sc = (a0 + a1) + (a2 + a3) + rpb[rrow[m] * NHEADS + hh] + mrow[m];
    const float p = __expf(sc);
    sum += p;
#pragma unroll
    for (int i = 0; i < HDIM; i++) o[i] = fmaf(p, vl[m][i], o[i]);
  }
  const float inv = 1.f / sum;
  bf16* orow = xout + (size_t)token * HID2 + CC + hh * HDIM;
#pragma unroll
  for (int i = 0; i < HDIM; i++) orow[i] = __float2bfloat16(o[i] * inv);
}

__global__ __launch_bounds__(64) void k_attn_mut_fb(
    const float* __restrict__ x, const float* __restrict__ g1,
    const float* __restrict__ b1, const float* __restrict__ wqkv,
    const float* __restrict__ bqkv, const float* __restrict__ pos,
    const float* __restrict__ mask, bf16* __restrict__ xout) {
  __shared__ float kl[64][HDIM];
  __shared__ float vl[64][HDIM];
  const int wi = blockIdx.x, hh = blockIdx.y, which = blockIdx.z;
  const int t = threadIdx.x;
  const int qtok = which ? t : 64 + t;
  const int ktok = which ? 64 + t : t;
  const float* pr = pos + (size_t)t * CC;
  float xv[CC];
  {
    const float* xr = x + token_src_offset(wi * NTOK + ktok);
#pragma unroll
    for (int k = 0; k < CC; k++) xv[k] = xr[k];
    ln120(xv, g1, b1);
#pragma unroll
    for (int k = 0; k < CC; k++) xv[k] += pr[k];
    for (int j = 0; j < HDIM; j++) {
      const int c = hh * HDIM + j;
      kl[t][j] = dot120(xv, wqkv + (size_t)(CC + c) * CC) + bqkv[CC + c];
      vl[t][j] = dot120(xv, wqkv + (size_t)(2 * CC + c) * CC) + bqkv[2 * CC + c];
    }
  }
  float q[HDIM];
  {
    const float* xr = x + token_src_offset(wi * NTOK + qtok);
#pragma unroll
    for (int k = 0; k < CC; k++) xv[k] = xr[k];
    ln120(xv, g1, b1);
#pragma unroll
    for (int k = 0; k < CC; k++) xv[k] += pr[k];
    for (int j = 0; j < HDIM; j++) {
      const int c = hh * HDIM + j;
      q[j] = (dot120(xv, wqkv + (size_t)c * CC) + bqkv[c]) * SCALE_F;
    }
  }
  __syncthreads();
  const float* mrow = mask + ((size_t)(wi & 255) * NTOK + t) * NTOK;
  float sum = 0.f;
  float o[HDIM];
#pragma unroll
  for (int i = 0; i < HDIM; i++) o[i] = 0.f;
  for (int m = 0; m < 64; m++) {
    float a0 = 0.f, a1 = 0.f, a2 = 0.f, a3 = 0.f;
#pragma unroll
    for (int i = 0; i < HDIM; i += 4) {
      a0 = fmaf(q[i], kl[m][i], a0);
      a1 = fmaf(q[i + 1], kl[m][i + 1], a1);
      a2 = fmaf(q[i + 2], kl[m][i + 2], a2);
      a3 = fmaf(q[i + 3], kl[m][i + 3], a3);
    }
    const float p = __expf((a0 + a1) + (a2 + a3) + mrow[m]);
    sum += p;
#pragma unroll
    for (int i = 0; i < HDIM; i++) o[i] = fmaf(p, vl[m][i], o[i]);
  }
  const float inv = 1.f / sum;
  const int orow_i = which ? 64 + t : t;
  bf16* orow = xout + (size_t)(wi * NTOK + orow_i) * HID2 + hh * HDIM;
#pragma unroll
  for (int i = 0; i < HDIM; i++) orow[i] = __float2bfloat16(o[i] * inv);
}

template <int HALF>
__global__ __launch_bounds__(256) void k_proj_fb(
    const bf16* __restrict__ xout, const float* __restrict__ pw,
    const float* __restrict__ pb, const float* __restrict__ xin,
    float* __restrict__ out) {
  const int token = blockIdx.x * 256 + threadIdx.x;
  float xv[CC];
  const bf16* xr = xout + (size_t)token * HID2 + HALF * CC;
#pragma unroll
  for (int k = 0; k < CC; k++) xv[k] = __bfloat162float(xr[k]);
  const size_t dst = token_src_offset(token);
  for (int o = 0; o < CC; o++) {
    const float acc = dot120(xv, pw + (size_t)o * HID2 + HALF * CC);
    if (HALF == 0)
      out[dst + o] = xin[dst + o] + pb[o] + acc;
    else
      out[dst + o] += acc;
  }
}

__global__ __launch_bounds__(256) void k_ffn1_fb(
    const float* __restrict__ xres, const float* __restrict__ g,
    const float* __restrict__ bb, const float* __restrict__ w11,
    const float* __restrict__ b11, const float* __restrict__ w12,
    const float* __restrict__ b12, bf16* __restrict__ hbuf) {
  const int row = blockIdx.x * 256 + threadIdx.x;
  const float* xr = xres + (size_t)row * CC;
  float xv[CC];
#pragma unroll
  for (int k = 0; k < CC; k++) xv[k] = xr[k];
  ln120(xv, g, bb);
  bf16* hr = hbuf + (size_t)row * HID2;
  for (int o = 0; o < HID2; o++) {
    const float a = b11[o] + dot120(xv, w11 + (size_t)o * CC);
    const float c = b12[o] + dot120(xv, w12 + (size_t)o * CC);
    const float ge = 0.5f * a * (1.f + erff(a * 0.70710678118654752f));
    hr[o] = __float2bfloat16(ge * c);
  }
}

template <int HALF>
__global__ __launch_bounds__(256) void k_ffn2_fb(
    const bf16* __restrict__ hbuf, const float* __restrict__ w2,
    const float* __restrict__ b2f, float* __restrict__ out) {
  const int row = blockIdx.x * 256 + threadIdx.x;
  float xv[CC];
  const bf16* xr = hbuf + (size_t)row * HID2 + HALF * CC;
#pragma unroll
  for (int k = 0; k < CC; k++) xv[k] = __bfloat162float(xr[k]);
  float* orow = out + (size_t)row * CC;
  for (int o = 0; o < CC; o++) {
    float acc = dot120(xv, w2 + (size_t)o * HID2 + HALF * CC);
    if (HALF == 0) acc += b2f[o];
    orow[o] += acc;
  }
}

// ---------------------------------------------------------------------------
extern "C" void kernel_launch(void* const* d_in, const int* in_sizes, int n_in,
                              void* d_out, int out_size, void* d_ws, size_t ws_size,
                              hipStream_t stream) {
  const float* x          = (const float*)d_in[0];
  const float* attn_mask  = (const float*)d_in[1];
  const float* g1         = (const float*)d_in[2];
  const float* b1         = (const float*)d_in[3];
  const float* qkv_self_w = (const float*)d_in[4];
  const float* qkv_self_b = (const float*)d_in[5];
  const float* qkv_mut_w  = (const float*)d_in[6];
  const float* qkv_mut_b  = (const float*)d_in[7];
  const float* proj_w     = (const float*)d_in[8];
  const float* proj_b     = (const float*)d_in[9];
  const float* rpb_table  = (const float*)d_in[10];
  const float* pos_bias   = (const float*)d_in[11];
  const float* g2         = (const float*)d_in[12];
  const float* b2         = (const float*)d_in[13];
  const float* fc11_w     = (const float*)d_in[14];
  const float* fc11_b     = (const float*)d_in[15];
  const float* fc12_w     = (const float*)d_in[16];
  const float* fc12_b     = (const float*)d_in[17];
  const float* fc2_w      = (const float*)d_in[18];
  const float* fc2_b      = (const float*)d_in[19];
  const int*   rpi        = (const int*)d_in[20];
  float* out = (float*)d_out;

  // ws layout (bytes):
  //   xout   @ 0           : 131072*256*2 = 67,108,864
  //   A1/A2  @ 67,108,864  : 131072*128*2 = 33,554,432 (A1 dead before A2 written)
  //   Bffn   @ 100,663,296 : 131,072
  //   Bfc2   @ 100,794,368 :  65,536
  //   Bproj  @ 100,859,904 :  65,536  -> total 100,925,440 (same gate as R3)
  // d_out doubles as scratch BEFORE proj overwrites it:
  //   Wself @ 0, Wmut @ 98,304, posq @ 196,608 (fp32), qkv-half @ 294,912
  //   (294,912 + 65536*384*2 = 50,626,560 <= 62,914,560)
  const bool fast = ws_size >= (size_t)100925440;

  if (fast) {
    bf16* xout  = (bf16*)d_ws;
    bf16* hbuf  = xout;
    bf16* A1    = (bf16*)((char*)d_ws + 67108864);
    bf16* A2    = A1;
    bf16* Bffn  = (bf16*)((char*)d_ws + 100663296);
    bf16* Bfc2  = Bffn + 65536;
    bf16* Bproj = Bfc2 + 32768;

    bf16*  Wself = (bf16*)d_out;
    bf16*  Wmut  = (bf16*)((char*)d_out + 98304);
    float* posq  = (float*)((char*)d_out + 196608);
    bf16*  qkvh  = (bf16*)((char*)d_out + 294912);

    k_prep<<<896, 256, 0, stream>>>(fc11_w, fc12_w, fc2_w, proj_w,
                                    qkv_self_w, qkv_self_b, qkv_mut_w, qkv_mut_b,
                                    Bffn, Bfc2, Bproj, Wself, Wmut);
    k_posq<<<96, 256, 0, stream>>>(pos_bias, qkv_mut_w, posq);
    k_a1<<<512, 256, 0, stream>>>(x, g1, b1, A1);
    for (int h = 0; h < 2; h++) {
      k_qkv_mfma<false><<<dim3(3, 512), 256, 0, stream>>>(A1, Wself, nullptr, qkvh, h * 65536);
      k_attn_self2<<<dim3(512, NHEADS), 128, 0, stream>>>(qkvh, attn_mask, rpb_table, rpi, xout, h * 512);
    }
    for (int h = 0; h < 2; h++) {
      k_qkv_mfma<true><<<dim3(3, 512), 256, 0, stream>>>(A1, Wmut, posq, qkvh, h * 65536);
      k_attn_mut2<<<dim3(512, NHEADS), 128, 0, stream>>>(qkvh, attn_mask, xout, h * 512);
    }
    k_out_mfma<true><<<dim3(1, 512), 256, 0, stream>>>(xout, Bproj, proj_b, x, out);
    k_ln2<<<512, 256, 0, stream>>>(out, g2, b2, A2);
    k_ffn1_mfma<<<dim3(4, 256), 256, 0, stream>>>(A2, Bffn, fc11_b, fc12_b, hbuf);
    k_out_mfma<false><<<dim3(1, 512), 256, 0, stream>>>(hbuf, Bfc2, fc2_b, nullptr, out);
  } else {
    bf16* xout = (bf16*)d_ws;
    bf16* hbuf = (bf16*)d_ws;
    k_attn_self_fb<<<dim3(1024, NHEADS), 128, 0, stream>>>(
        x, g1, b1, qkv_self_w, qkv_self_b, attn_mask, rpb_table, rpi, xout);
    k_attn_mut_fb<<<dim3(1024, NHEADS, 2), 64, 0, stream>>>(
        x, g1, b1, qkv_mut_w, qkv_mut_b, pos_bias, attn_mask, xout);
    k_proj_fb<0><<<512, 256, 0, stream>>>(xout, proj_w, proj_b, x, out);
    k_proj_fb<1><<<512, 256, 0, stream>>>(xout, proj_w, proj_b, x, out);
    k_ffn1_fb<<<512, 256, 0, stream>>>(out, g2, b2, fc11_w, fc11_b, fc12_w, fc12_b, hbuf);
    k_ffn2_fb<0><<<512, 256, 0, stream>>>(hbuf, fc2_w, fc2_b, out);
    k_ffn2_fb<1><<<512, 256, 0, stream>>>(hbuf, fc2_w, fc2_b, out);
  }
}